// Round 7
// baseline (228.084 us; speedup 1.0000x reference)
//
#include <hip/hip_runtime.h>
#include <stdint.h>
#include <math.h>

typedef __bf16 bf16;
typedef __bf16 bf16x4 __attribute__((ext_vector_type(4)));
typedef __bf16 bf16x8 __attribute__((ext_vector_type(8)));
typedef float f32x4 __attribute__((ext_vector_type(4)));

#define MFMA16(a, b, c) __builtin_amdgcn_mfma_f32_16x16x32_bf16((a), (b), (c), 0, 0, 0)

typedef __attribute__((address_space(1))) void* as1v;
typedef __attribute__((address_space(3))) void* as3v;

__device__ __forceinline__ void async_ld16(const void* g, void* l) {
  __builtin_amdgcn_global_load_lds((as1v)(uintptr_t)g,
                                   (as3v)(unsigned int)(uintptr_t)l, 16, 0, 0);
}

// ---------------- fused cast fp32 -> bf16 for all three inputs --------------
__global__ __launch_bounds__(256) void cast3_k(const float* __restrict__ x,
                                               const float* __restrict__ wq,
                                               const float* __restrict__ wp,
                                               bf16* __restrict__ xb,
                                               bf16* __restrict__ wqb,
                                               bf16* __restrict__ wpb) {
  const long i = (long)blockIdx.x * 256 + threadIdx.x;
  const float4* src;
  bf16x4* dst;
  long off;
  if (i < 2097152L) {
    src = (const float4*)x;  dst = (bf16x4*)xb;  off = i;
  } else if (i < 2097152L + 786432L) {
    src = (const float4*)wq; dst = (bf16x4*)wqb; off = i - 2097152L;
  } else {
    src = (const float4*)wp; dst = (bf16x4*)wpb; off = i - 2097152L - 786432L;
  }
  float4 v = src[off];
  bf16x4 o;
  o[0] = (bf16)v.x; o[1] = (bf16)v.y; o[2] = (bf16)v.z; o[3] = (bf16)v.w;
  dst[off] = o;
}

// ---------------- QKV GEMM v4 (R2/R3-proven): 128x192, counted-vmcnt --------
// Exact R3 source. 2-barrier pipeline, vmcnt(10), no XCD remap (R6 showed the
// A-panel remap raised FETCH 74->88 MB with no time gain).
__global__ __launch_bounds__(256, 2) void gemm_qkv(const bf16* __restrict__ A,
                                                   const bf16* __restrict__ Bm,
                                                   bf16* __restrict__ qb,
                                                   bf16* __restrict__ kb,
                                                   bf16* __restrict__ vth) {
  __shared__ bf16 As[2][128 * 64];  // 2 x 16 KB
  __shared__ bf16 Bs[2][192 * 64];  // 2 x 24 KB
  const int tid  = threadIdx.x;
  const int lane = tid & 63;
  const int wv   = tid >> 6;   // 0..3
  const int wm   = wv >> 1;    // 0..1: C rows [wm*64, +64)
  const int wn   = wv & 1;     // 0..1: C cols [wn*96, +96)
  const int lr   = lane & 15;
  const int quad = lane >> 4;
  const long m0 = (long)blockIdx.y * 128;
  const long n0 = (long)blockIdx.x * 192;

  const int srow = lane >> 3;
  const int scg  = (lane & 7) ^ srow;
  const int swz  = lr & 7;

  const f32x4 fz = {0.f, 0.f, 0.f, 0.f};
  f32x4 acc[4][6];
#pragma unroll
  for (int i = 0; i < 4; ++i)
#pragma unroll
    for (int j = 0; j < 6; ++j) acc[i][j] = fz;

#define STAGE_QKV(kt, bufi)                                                        \
  do {                                                                             \
    const long kk = (long)(kt) * 64;                                               \
    _Pragma("unroll") for (int i_ = 0; i_ < 4; ++i_)                               \
        async_ld16(&A[(m0 + i_ * 32 + wv * 8 + srow) * 1024 + kk + scg * 8],       \
                   &As[bufi][(i_ * 32 + wv * 8) * 64]);                            \
    _Pragma("unroll") for (int i_ = 0; i_ < 6; ++i_)                               \
        async_ld16(&Bm[(n0 + i_ * 32 + wv * 8 + srow) * 1024 + kk + scg * 8],      \
                   &Bs[bufi][(i_ * 32 + wv * 8) * 64]);                            \
  } while (0)

  STAGE_QKV(0, 0);

#pragma unroll 2
  for (int t = 0; t < 16; ++t) {
    const int cur = t & 1;
    if (t < 15) {
      STAGE_QKV(t + 1, cur ^ 1);
      asm volatile("s_waitcnt vmcnt(10)" ::: "memory");  // tile t resident (own 10)
    } else {
      asm volatile("s_waitcnt vmcnt(0)" ::: "memory");   // final tile drain
    }
    __builtin_amdgcn_s_barrier();  // B1: all waves' tile-t DMA visible

    bf16x8 af[2][4], bfr[2][6];
#pragma unroll
    for (int ds = 0; ds < 2; ++ds) {
      const int slot = ((ds << 2) + quad) ^ swz;  // frag row&7 == lr&7 == swz
#pragma unroll
      for (int mi = 0; mi < 4; ++mi)
        af[ds][mi] = *(const bf16x8*)&As[cur][(wm * 64 + mi * 16 + lr) * 64 + slot * 8];
#pragma unroll
      for (int ni = 0; ni < 6; ++ni)
        bfr[ds][ni] = *(const bf16x8*)&Bs[cur][(wn * 96 + ni * 16 + lr) * 64 + slot * 8];
    }
#pragma unroll
    for (int ds = 0; ds < 2; ++ds)
#pragma unroll
      for (int mi = 0; mi < 4; ++mi)
#pragma unroll
        for (int ni = 0; ni < 6; ++ni)
          acc[mi][ni] = MFMA16(af[ds][mi], bfr[ds][ni], acc[mi][ni]);

    if (t < 15) __builtin_amdgcn_s_barrier();  // B2: reads done before t+2 DMA
  }
#undef STAGE_QKV

  const float kS = 0.18033688f;  // 0.125 * log2(e)
#pragma unroll
  for (int mi = 0; mi < 4; ++mi) {
    const long row = m0 + wm * 64 + mi * 16 + quad * 4;
#pragma unroll
    for (int ni = 0; ni < 6; ++ni) {
      const long col = n0 + wn * 96 + ni * 16 + lr;
      if (col < 1024) {  // Q, pre-scaled
#pragma unroll
        for (int r = 0; r < 4; ++r) qb[(row + r) * 1024 + col] = (bf16)(acc[mi][ni][r] * kS);
      } else if (col < 2048) {  // K
        const long kc = col - 1024;
#pragma unroll
        for (int r = 0; r < 4; ++r) kb[(row + r) * 1024 + kc] = (bf16)(acc[mi][ni][r]);
      } else {  // V transposed: vth[(b*16+h)*64 + d][t], 4 consecutive t/lane
        const long vcol = col - 2048;
        const long h = vcol >> 6, d = vcol & 63;
        const long b = row >> 11;
        const long tt = row & 2047;
        bf16x4 pk;
#pragma unroll
        for (int r = 0; r < 4; ++r) pk[r] = (bf16)(acc[mi][ni][r]);
        *(bf16x4*)&vth[(((b << 4) + h) * 64 + d) * 2048 + tt] = pk;
      }
    }
  }
}

// ---------------- proj GEMM v2: 128x128, 4 waves, counted-vmcnt pipeline ----
// (unchanged from R3)
__global__ __launch_bounds__(256, 2) void gemm_proj(const bf16* __restrict__ A,
                                                    const bf16* __restrict__ Bm,
                                                    float* __restrict__ C) {
  __shared__ bf16 As[2][128 * 64];  // 2 x 16 KB
  __shared__ bf16 Bs[2][128 * 64];  // 2 x 16 KB
  const int tid  = threadIdx.x;
  const int lane = tid & 63;
  const int wv   = tid >> 6;   // 0..3
  const int wm   = wv >> 1;    // 0..1: C rows [wm*64, +64)
  const int wn   = wv & 1;     // 0..1: C cols [wn*64, +64)
  const int lr   = lane & 15;
  const int quad = lane >> 4;
  const long m0 = (long)blockIdx.y * 128;
  const long n0 = (long)blockIdx.x * 128;

  const int srow = lane >> 3;
  const int scg  = (lane & 7) ^ srow;
  const int swz  = lr & 7;

  const f32x4 fz = {0.f, 0.f, 0.f, 0.f};
  f32x4 acc[4][4];
#pragma unroll
  for (int i = 0; i < 4; ++i)
#pragma unroll
    for (int j = 0; j < 4; ++j) acc[i][j] = fz;

#define STAGE_PROJ(kt, bufi)                                                       \
  do {                                                                             \
    const long kk = (long)(kt) * 64;                                               \
    _Pragma("unroll") for (int i_ = 0; i_ < 4; ++i_) {                             \
      const int rb = i_ * 32 + wv * 8;                                             \
      async_ld16(&A[(m0 + rb + srow) * 1024 + kk + scg * 8], &As[bufi][rb * 64]);  \
      async_ld16(&Bm[(n0 + rb + srow) * 1024 + kk + scg * 8], &Bs[bufi][rb * 64]); \
    }                                                                              \
  } while (0)

  STAGE_PROJ(0, 0);

#pragma unroll 2
  for (int t = 0; t < 16; ++t) {
    const int cur = t & 1;
    if (t < 15) {
      STAGE_PROJ(t + 1, cur ^ 1);
      asm volatile("s_waitcnt vmcnt(8)" ::: "memory");  // tile t resident (own 8)
    } else {
      asm volatile("s_waitcnt vmcnt(0)" ::: "memory");
    }
    __builtin_amdgcn_s_barrier();  // B1

    bf16x8 af[2][4], bfr[2][4];
#pragma unroll
    for (int ds = 0; ds < 2; ++ds) {
      const int slot = ((ds << 2) + quad) ^ swz;
#pragma unroll
      for (int mi = 0; mi < 4; ++mi)
        af[ds][mi] = *(const bf16x8*)&As[cur][(wm * 64 + mi * 16 + lr) * 64 + slot * 8];
#pragma unroll
      for (int ni = 0; ni < 4; ++ni)
        bfr[ds][ni] = *(const bf16x8*)&Bs[cur][(wn * 64 + ni * 16 + lr) * 64 + slot * 8];
    }
#pragma unroll
    for (int ds = 0; ds < 2; ++ds)
#pragma unroll
      for (int mi = 0; mi < 4; ++mi)
#pragma unroll
        for (int ni = 0; ni < 4; ++ni)
          acc[mi][ni] = MFMA16(af[ds][mi], bfr[ds][ni], acc[mi][ni]);

    if (t < 15) __builtin_amdgcn_s_barrier();  // B2
  }
#undef STAGE_PROJ

#pragma unroll
  for (int mi = 0; mi < 4; ++mi) {
    const long row = m0 + wm * 64 + mi * 16 + quad * 4;
#pragma unroll
    for (int ni = 0; ni < 4; ++ni) {
      const long col = n0 + wn * 64 + ni * 16 + lr;
#pragma unroll
      for (int r = 0; r < 4; ++r) C[(row + r) * 1024 + col] = acc[mi][ni][r];
    }
  }
}

// ---------------- causal flash attention v9 --------------------------------
// = R3/R4-proven v6 (two-half structure, XCD remap, no setprio)
// + Ps slot-rotation swizzle: logical 16B-slot s -> physical (s+row)&7, same
//   map on write and read (bijective per row). Kills the stride-72 4-way bank
//   clustering on P writes (g=(9*row+s)%8) and ap b128 reads; new pattern is
//   <=2 accesses/bank/cycle (free). Signature: SQ_LDS_BANK_CONFLICT 3.24M -> <0.8M.
__global__ __launch_bounds__(256, 2) void flash_attn9(const bf16* __restrict__ q,
                                                      const bf16* __restrict__ k,
                                                      const bf16* __restrict__ vth,
                                                      bf16* __restrict__ y) {
  __shared__ bf16 Ks[2][64 * 64];  // [buf][key][d-swizzled]
  __shared__ bf16 Vt[64 * 64];     // [d][key-swizzled]
  __shared__ bf16 Ps[4][32 * 72];  // per-wave P[qloc][slot-rotated], stride 72
  const int tid  = threadIdx.x;
  const int lane = tid & 63;
  const int wv   = tid >> 6;       // 0..3
  const int lr   = lane & 15;
  const int quad = lane >> 4;
  const int lin  = blockIdx.x + (blockIdx.y << 3);
  const int xcd  = lin & 7;
  const int slot = lin >> 3;
  const int p    = slot & 7;                  // 0..7 (q-tile pair)
  const int bh   = ((slot >> 3) << 3) | xcd;  // 8 p-blocks of bh share an XCD
  const int b = bh >> 4, h = bh & 15;
  const bf16* qp = q + ((size_t)b * 2048) * 1024 + h * 64;
  const bf16* kp = k + ((size_t)b * 2048) * 1024 + h * 64;
  const bf16* vp = vth + (size_t)bh * 64 * 2048;
  bf16* yp = y + ((size_t)b * 2048) * 1024 + h * 64;

  const int stg_row = lane >> 3;
  const int stg_cg  = (lane & 7) ^ stg_row;
  const int swz     = lr & 7;

  bf16x8 ones;
#pragma unroll
  for (int j = 0; j < 8; ++j) ones[j] = (bf16)1.0f;
  const f32x4 fz = {0.f, 0.f, 0.f, 0.f};

  for (int half = 0; half < 2; ++half) {
    const int qt = half ? p : 15 - p;
    const int q0 = qt * 128;
    const int kb_max = 2 * qt + 1;
    const int kmax_w = 2 * qt + (wv >> 1);  // waves 0,1 end one k-tile early

    bf16x8 qf[2][2];
#pragma unroll
    for (int nq = 0; nq < 2; ++nq) {
      const int qrow = q0 + wv * 32 + nq * 16 + lr;
#pragma unroll
      for (int ds = 0; ds < 2; ++ds)
        qf[nq][ds] = *(const bf16x8*)(qp + (size_t)qrow * 1024 + ds * 32 + quad * 8);
    }

    f32x4 o[2][4];
    f32x4 lacc[2];
#pragma unroll
    for (int nq = 0; nq < 2; ++nq) {
      lacc[nq] = fz;
#pragma unroll
      for (int nf = 0; nf < 4; ++nf) o[nq][nf] = fz;
    }

    __syncthreads();  // prev half's Vt/Ps reads complete
#pragma unroll
    for (int i = 0; i < 2; ++i) {
      const int r = i * 32 + wv * 8 + stg_row;
      async_ld16(kp + (size_t)r * 1024 + stg_cg * 8, &Ks[0][(i * 32 + wv * 8) * 64]);
    }

    for (int kt = 0; kt <= kb_max; ++kt) {
      const int k0 = kt * 64;
      const int cb = kt & 1;
      __syncthreads();  // B1
      if (kt < kb_max) {
#pragma unroll
        for (int i = 0; i < 2; ++i) {
          const int r = i * 32 + wv * 8 + stg_row;
          async_ld16(kp + (size_t)(k0 + 64 + r) * 1024 + stg_cg * 8,
                     &Ks[cb ^ 1][(i * 32 + wv * 8) * 64]);
        }
      }
#pragma unroll
      for (int i = 0; i < 2; ++i) {
        const int r = i * 32 + wv * 8 + stg_row;
        async_ld16(vp + (size_t)r * 2048 + k0 + stg_cg * 8, &Vt[(i * 32 + wv * 8) * 64]);
      }

      const bool act = (kt <= kmax_w);
      bf16x8 ap[2][2];
      if (act) {
        f32x4 s[2][4];
#pragma unroll
        for (int nq = 0; nq < 2; ++nq)
#pragma unroll
          for (int mi = 0; mi < 4; ++mi) s[nq][mi] = fz;
#pragma unroll
        for (int ds = 0; ds < 2; ++ds)
#pragma unroll
          for (int mi = 0; mi < 4; ++mi) {
            const bf16x8 ak =
                *(const bf16x8*)&Ks[cb][(mi * 16 + lr) * 64 + (((ds << 2) + quad) ^ swz) * 8];
            s[0][mi] = MFMA16(ak, qf[0][ds], s[0][mi]);
            s[1][mi] = MFMA16(ak, qf[1][ds], s[1][mi]);
          }

        if (kt < kmax_w) {
#pragma unroll
          for (int nq = 0; nq < 2; ++nq) {
            const int qloc = nq * 16 + lr;
#pragma unroll
            for (int mi = 0; mi < 4; ++mi) {
              bf16x4 pb;
#pragma unroll
              for (int r = 0; r < 4; ++r) pb[r] = (bf16)__builtin_amdgcn_exp2f(s[nq][mi][r]);
              const int ls = ((mi * 2 + (quad >> 1)) + qloc) & 7;  // rotated slot
              *(bf16x4*)&Ps[wv][qloc * 72 + (ls << 3) + ((quad & 1) << 2)] = pb;
            }
          }
        } else {
          const int kofs = k0 - q0 - wv * 32;  // mask iff keyloc + kofs > qloc
#pragma unroll
          for (int nq = 0; nq < 2; ++nq) {
            const int qloc = nq * 16 + lr;
#pragma unroll
            for (int mi = 0; mi < 4; ++mi) {
              bf16x4 pb;
#pragma unroll
              for (int r = 0; r < 4; ++r) {
                float pv = __builtin_amdgcn_exp2f(s[nq][mi][r]);
                if (mi * 16 + quad * 4 + r + kofs > qloc) pv = 0.0f;
                pb[r] = (bf16)pv;
              }
              const int ls = ((mi * 2 + (quad >> 1)) + qloc) & 7;  // rotated slot
              *(bf16x4*)&Ps[wv][qloc * 72 + (ls << 3) + ((quad & 1) << 2)] = pb;
            }
          }
        }
#pragma unroll
        for (int ks = 0; ks < 2; ++ks) {
          const int rs = (ks * 4 + quad + lr) & 7;  // rotated slot (row&7 == lr&7)
          ap[0][ks] = *(const bf16x8*)&Ps[wv][(lr) * 72 + (rs << 3)];
          ap[1][ks] = *(const bf16x8*)&Ps[wv][(16 + lr) * 72 + (rs << 3)];
        }
      }

      __syncthreads();  // B2: drains Vt(kt) + Ks(kt+1), issued an S-phase ago

      if (act) {
#pragma unroll
        for (int ks = 0; ks < 2; ++ks) {
          lacc[0] = MFMA16(ap[0][ks], ones, lacc[0]);
          lacc[1] = MFMA16(ap[1][ks], ones, lacc[1]);
#pragma unroll
          for (int nf = 0; nf < 4; ++nf) {
            const bf16x8 bv =
                *(const bf16x8*)&Vt[(nf * 16 + lr) * 64 + (((ks << 2) + quad) ^ swz) * 8];
            o[0][nf] = MFMA16(ap[0][ks], bv, o[0][nf]);
            o[1][nf] = MFMA16(ap[1][ks], bv, o[1][nf]);
          }
        }
      }
    }

#pragma unroll
    for (int nq = 0; nq < 2; ++nq)
#pragma unroll
      for (int r = 0; r < 4; ++r) {
        const float inv = __builtin_amdgcn_rcpf(lacc[nq][r]);
        const int t = q0 + wv * 32 + nq * 16 + quad * 4 + r;
#pragma unroll
        for (int nf = 0; nf < 4; ++nf)
          yp[(size_t)t * 1024 + nf * 16 + lr] = (bf16)(o[nq][nf][r] * inv);
      }
  }
}

// ---------------------------------------------------------------------------
extern "C" void kernel_launch(void* const* d_in, const int* in_sizes, int n_in,
                              void* d_out, int out_size, void* d_ws, size_t ws_size,
                              hipStream_t stream) {
  const float* x      = (const float*)d_in[0];
  const float* w_qkv  = (const float*)d_in[1];
  const float* w_proj = (const float*)d_in[2];
  float* out = (float*)d_out;
  char* ws = (char*)d_ws;

  // workspace carve (88 MiB)
  bf16* xb   = (bf16*)(ws);                        // 16 MiB  [8192,1024]
  bf16* wqkb = (bf16*)(ws + (16ull << 20));        //  6 MiB  [3072,1024]
  bf16* wpb  = (bf16*)(ws + (22ull << 20));        //  2 MiB  [1024,1024]
  bf16* qb   = (bf16*)(ws + (24ull << 20));        // 16 MiB  [8192,1024] pre-scaled Q
  bf16* kbuf = (bf16*)(ws + (40ull << 20));        // 16 MiB  [8192,1024]
  bf16* vth  = (bf16*)(ws + (56ull << 20));        // 16 MiB  [64bh,64d,2048t]
  bf16* yb   = (bf16*)(ws + (72ull << 20));        // 16 MiB  [8192,1024]

  cast3_k<<<dim3(12288), 256, 0, stream>>>(x, w_qkv, w_proj, xb, wqkb, wpb);
  gemm_qkv<<<dim3(16, 64), 256, 0, stream>>>(xb, wqkb, qb, kbuf, vth);
  flash_attn9<<<dim3(8, 64), 256, 0, stream>>>(qb, kbuf, vth, yb);
  gemm_proj<<<dim3(8, 64), 256, 0, stream>>>(yb, wpb, out);
}

// Round 8
// 215.467 us; speedup vs baseline: 1.0586x; 1.0586x over previous
//
#include <hip/hip_runtime.h>
#include <stdint.h>
#include <math.h>

typedef __bf16 bf16;
typedef __bf16 bf16x4 __attribute__((ext_vector_type(4)));
typedef __bf16 bf16x8 __attribute__((ext_vector_type(8)));
typedef float f32x4 __attribute__((ext_vector_type(4)));

#define MFMA16(a, b, c) __builtin_amdgcn_mfma_f32_16x16x32_bf16((a), (b), (c), 0, 0, 0)

typedef __attribute__((address_space(1))) void* as1v;
typedef __attribute__((address_space(3))) void* as3v;

__device__ __forceinline__ void async_ld16(const void* g, void* l) {
  __builtin_amdgcn_global_load_lds((as1v)(uintptr_t)g,
                                   (as3v)(unsigned int)(uintptr_t)l, 16, 0, 0);
}

// ---------------- fused cast fp32 -> bf16 for all three inputs --------------
__global__ __launch_bounds__(256) void cast3_k(const float* __restrict__ x,
                                               const float* __restrict__ wq,
                                               const float* __restrict__ wp,
                                               bf16* __restrict__ xb,
                                               bf16* __restrict__ wqb,
                                               bf16* __restrict__ wpb) {
  const long i = (long)blockIdx.x * 256 + threadIdx.x;
  const float4* src;
  bf16x4* dst;
  long off;
  if (i < 2097152L) {
    src = (const float4*)x;  dst = (bf16x4*)xb;  off = i;
  } else if (i < 2097152L + 786432L) {
    src = (const float4*)wq; dst = (bf16x4*)wqb; off = i - 2097152L;
  } else {
    src = (const float4*)wp; dst = (bf16x4*)wpb; off = i - 2097152L - 786432L;
  }
  float4 v = src[off];
  bf16x4 o;
  o[0] = (bf16)v.x; o[1] = (bf16)v.y; o[2] = (bf16)v.z; o[3] = (bf16)v.w;
  dst[off] = o;
}

// ---------------- QKV GEMM v4 (R2/R3-proven): 128x192, counted-vmcnt --------
// Exact R3 source.
__global__ __launch_bounds__(256, 2) void gemm_qkv(const bf16* __restrict__ A,
                                                   const bf16* __restrict__ Bm,
                                                   bf16* __restrict__ qb,
                                                   bf16* __restrict__ kb,
                                                   bf16* __restrict__ vth) {
  __shared__ bf16 As[2][128 * 64];  // 2 x 16 KB
  __shared__ bf16 Bs[2][192 * 64];  // 2 x 24 KB
  const int tid  = threadIdx.x;
  const int lane = tid & 63;
  const int wv   = tid >> 6;   // 0..3
  const int wm   = wv >> 1;    // 0..1: C rows [wm*64, +64)
  const int wn   = wv & 1;     // 0..1: C cols [wn*96, +96)
  const int lr   = lane & 15;
  const int quad = lane >> 4;
  const long m0 = (long)blockIdx.y * 128;
  const long n0 = (long)blockIdx.x * 192;

  const int srow = lane >> 3;
  const int scg  = (lane & 7) ^ srow;
  const int swz  = lr & 7;

  const f32x4 fz = {0.f, 0.f, 0.f, 0.f};
  f32x4 acc[4][6];
#pragma unroll
  for (int i = 0; i < 4; ++i)
#pragma unroll
    for (int j = 0; j < 6; ++j) acc[i][j] = fz;

#define STAGE_QKV(kt, bufi)                                                        \
  do {                                                                             \
    const long kk = (long)(kt) * 64;                                               \
    _Pragma("unroll") for (int i_ = 0; i_ < 4; ++i_)                               \
        async_ld16(&A[(m0 + i_ * 32 + wv * 8 + srow) * 1024 + kk + scg * 8],       \
                   &As[bufi][(i_ * 32 + wv * 8) * 64]);                            \
    _Pragma("unroll") for (int i_ = 0; i_ < 6; ++i_)                               \
        async_ld16(&Bm[(n0 + i_ * 32 + wv * 8 + srow) * 1024 + kk + scg * 8],      \
                   &Bs[bufi][(i_ * 32 + wv * 8) * 64]);                            \
  } while (0)

  STAGE_QKV(0, 0);

#pragma unroll 2
  for (int t = 0; t < 16; ++t) {
    const int cur = t & 1;
    if (t < 15) {
      STAGE_QKV(t + 1, cur ^ 1);
      asm volatile("s_waitcnt vmcnt(10)" ::: "memory");  // tile t resident (own 10)
    } else {
      asm volatile("s_waitcnt vmcnt(0)" ::: "memory");   // final tile drain
    }
    __builtin_amdgcn_s_barrier();  // B1: all waves' tile-t DMA visible

    bf16x8 af[2][4], bfr[2][6];
#pragma unroll
    for (int ds = 0; ds < 2; ++ds) {
      const int slot = ((ds << 2) + quad) ^ swz;  // frag row&7 == lr&7 == swz
#pragma unroll
      for (int mi = 0; mi < 4; ++mi)
        af[ds][mi] = *(const bf16x8*)&As[cur][(wm * 64 + mi * 16 + lr) * 64 + slot * 8];
#pragma unroll
      for (int ni = 0; ni < 6; ++ni)
        bfr[ds][ni] = *(const bf16x8*)&Bs[cur][(wn * 96 + ni * 16 + lr) * 64 + slot * 8];
    }
#pragma unroll
    for (int ds = 0; ds < 2; ++ds)
#pragma unroll
      for (int mi = 0; mi < 4; ++mi)
#pragma unroll
        for (int ni = 0; ni < 6; ++ni)
          acc[mi][ni] = MFMA16(af[ds][mi], bfr[ds][ni], acc[mi][ni]);

    if (t < 15) __builtin_amdgcn_s_barrier();  // B2: reads done before t+2 DMA
  }
#undef STAGE_QKV

  const float kS = 0.18033688f;  // 0.125 * log2(e)
#pragma unroll
  for (int mi = 0; mi < 4; ++mi) {
    const long row = m0 + wm * 64 + mi * 16 + quad * 4;
#pragma unroll
    for (int ni = 0; ni < 6; ++ni) {
      const long col = n0 + wn * 96 + ni * 16 + lr;
      if (col < 1024) {  // Q, pre-scaled
#pragma unroll
        for (int r = 0; r < 4; ++r) qb[(row + r) * 1024 + col] = (bf16)(acc[mi][ni][r] * kS);
      } else if (col < 2048) {  // K
        const long kc = col - 1024;
#pragma unroll
        for (int r = 0; r < 4; ++r) kb[(row + r) * 1024 + kc] = (bf16)(acc[mi][ni][r]);
      } else {  // V transposed: vth[(b*16+h)*64 + d][t], 4 consecutive t/lane
        const long vcol = col - 2048;
        const long h = vcol >> 6, d = vcol & 63;
        const long b = row >> 11;
        const long tt = row & 2047;
        bf16x4 pk;
#pragma unroll
        for (int r = 0; r < 4; ++r) pk[r] = (bf16)(acc[mi][ni][r]);
        *(bf16x4*)&vth[(((b << 4) + h) * 64 + d) * 2048 + tt] = pk;
      }
    }
  }
}

// ---------------- proj GEMM v2: 128x128, 4 waves, counted-vmcnt pipeline ----
// (unchanged from R3)
__global__ __launch_bounds__(256, 2) void gemm_proj(const bf16* __restrict__ A,
                                                    const bf16* __restrict__ Bm,
                                                    float* __restrict__ C) {
  __shared__ bf16 As[2][128 * 64];  // 2 x 16 KB
  __shared__ bf16 Bs[2][128 * 64];  // 2 x 16 KB
  const int tid  = threadIdx.x;
  const int lane = tid & 63;
  const int wv   = tid >> 6;   // 0..3
  const int wm   = wv >> 1;    // 0..1: C rows [wm*64, +64)
  const int wn   = wv & 1;     // 0..1: C cols [wn*64, +64)
  const int lr   = lane & 15;
  const int quad = lane >> 4;
  const long m0 = (long)blockIdx.y * 128;
  const long n0 = (long)blockIdx.x * 128;

  const int srow = lane >> 3;
  const int scg  = (lane & 7) ^ srow;
  const int swz  = lr & 7;

  const f32x4 fz = {0.f, 0.f, 0.f, 0.f};
  f32x4 acc[4][4];
#pragma unroll
  for (int i = 0; i < 4; ++i)
#pragma unroll
    for (int j = 0; j < 4; ++j) acc[i][j] = fz;

#define STAGE_PROJ(kt, bufi)                                                       \
  do {                                                                             \
    const long kk = (long)(kt) * 64;                                               \
    _Pragma("unroll") for (int i_ = 0; i_ < 4; ++i_) {                             \
      const int rb = i_ * 32 + wv * 8;                                             \
      async_ld16(&A[(m0 + rb + srow) * 1024 + kk + scg * 8], &As[bufi][rb * 64]);  \
      async_ld16(&Bm[(n0 + rb + srow) * 1024 + kk + scg * 8], &Bs[bufi][rb * 64]); \
    }                                                                              \
  } while (0)

  STAGE_PROJ(0, 0);

#pragma unroll 2
  for (int t = 0; t < 16; ++t) {
    const int cur = t & 1;
    if (t < 15) {
      STAGE_PROJ(t + 1, cur ^ 1);
      asm volatile("s_waitcnt vmcnt(8)" ::: "memory");  // tile t resident (own 8)
    } else {
      asm volatile("s_waitcnt vmcnt(0)" ::: "memory");
    }
    __builtin_amdgcn_s_barrier();  // B1

    bf16x8 af[2][4], bfr[2][4];
#pragma unroll
    for (int ds = 0; ds < 2; ++ds) {
      const int slot = ((ds << 2) + quad) ^ swz;
#pragma unroll
      for (int mi = 0; mi < 4; ++mi)
        af[ds][mi] = *(const bf16x8*)&As[cur][(wm * 64 + mi * 16 + lr) * 64 + slot * 8];
#pragma unroll
      for (int ni = 0; ni < 4; ++ni)
        bfr[ds][ni] = *(const bf16x8*)&Bs[cur][(wn * 64 + ni * 16 + lr) * 64 + slot * 8];
    }
#pragma unroll
    for (int ds = 0; ds < 2; ++ds)
#pragma unroll
      for (int mi = 0; mi < 4; ++mi)
#pragma unroll
        for (int ni = 0; ni < 4; ++ni)
          acc[mi][ni] = MFMA16(af[ds][mi], bfr[ds][ni], acc[mi][ni]);

    if (t < 15) __builtin_amdgcn_s_barrier();  // B2
  }
#undef STAGE_PROJ

#pragma unroll
  for (int mi = 0; mi < 4; ++mi) {
    const long row = m0 + wm * 64 + mi * 16 + quad * 4;
#pragma unroll
    for (int ni = 0; ni < 4; ++ni) {
      const long col = n0 + wn * 64 + ni * 16 + lr;
#pragma unroll
      for (int r = 0; r < 4; ++r) C[(row + r) * 1024 + col] = acc[mi][ni][r];
    }
  }
}

// ---------------- causal flash attention v10: single-barrier pipeline -------
// = v6 body (XCD remap, un-swizzled Ps — R7's rotation reverted) with the
// sync structure rebuilt on the R2-proven counted-wait pattern:
//   - Vt double-buffered (+8 KB, LDS 50 KB)
//   - Ks(t+1) AND Vt(t+1) prefetched during iter t
//   - ONE raw s_barrier per iter, preceded by s_waitcnt vmcnt(0) on loads
//     issued a FULL ITERATION earlier (vs v6's two __syncthreads with the
//     second draining DMA issued only an S-phase earlier).
// Hazards: staging of buf[(t+1)&1] is issued after the barrier every wave
// crossed AFTER its iter-(t-1) reads of that buffer (LDS reads retire before
// barrier arrival); Ps is wave-private (write->read needs only lgkmcnt, as in
// v6); half-prologue staging of buf0 is safe because the prev half's last
// buf0 readers crossed its final barrier (last iter parity is odd). Barrier
// counts are wave-uniform.
__global__ __launch_bounds__(256, 2) void flash_attn10(const bf16* __restrict__ q,
                                                       const bf16* __restrict__ k,
                                                       const bf16* __restrict__ vth,
                                                       bf16* __restrict__ y) {
  __shared__ bf16 Ks[2][64 * 64];  // [buf][key][d-swizzled]   16 KB
  __shared__ bf16 Vt[2][64 * 64];  // [buf][d][key-swizzled]   16 KB
  __shared__ bf16 Ps[4][32 * 72];  // per-wave P[qloc][key]    18 KB
  const int tid  = threadIdx.x;
  const int lane = tid & 63;
  const int wv   = tid >> 6;       // 0..3
  const int lr   = lane & 15;
  const int quad = lane >> 4;
  const int lin  = blockIdx.x + (blockIdx.y << 3);
  const int xcd  = lin & 7;
  const int slot = lin >> 3;
  const int p    = slot & 7;                  // 0..7 (q-tile pair)
  const int bh   = ((slot >> 3) << 3) | xcd;  // 8 p-blocks of bh share an XCD
  const int b = bh >> 4, h = bh & 15;
  const bf16* qp = q + ((size_t)b * 2048) * 1024 + h * 64;
  const bf16* kp = k + ((size_t)b * 2048) * 1024 + h * 64;
  const bf16* vp = vth + (size_t)bh * 64 * 2048;
  bf16* yp = y + ((size_t)b * 2048) * 1024 + h * 64;

  const int stg_row = lane >> 3;
  const int stg_cg  = (lane & 7) ^ stg_row;
  const int swz     = lr & 7;

  bf16x8 ones;
#pragma unroll
  for (int j = 0; j < 8; ++j) ones[j] = (bf16)1.0f;
  const f32x4 fz = {0.f, 0.f, 0.f, 0.f};

  for (int half = 0; half < 2; ++half) {
    const int qt = half ? p : 15 - p;
    const int q0 = qt * 128;
    const int kb_max = 2 * qt + 1;
    const int kmax_w = 2 * qt + (wv >> 1);  // waves 0,1 end one k-tile early

    bf16x8 qf[2][2];
#pragma unroll
    for (int nq = 0; nq < 2; ++nq) {
      const int qrow = q0 + wv * 32 + nq * 16 + lr;
#pragma unroll
      for (int ds = 0; ds < 2; ++ds)
        qf[nq][ds] = *(const bf16x8*)(qp + (size_t)qrow * 1024 + ds * 32 + quad * 8);
    }

    f32x4 o[2][4];
    f32x4 lacc[2];
#pragma unroll
    for (int nq = 0; nq < 2; ++nq) {
      lacc[nq] = fz;
#pragma unroll
      for (int nf = 0; nf < 4; ++nf) o[nq][nf] = fz;
    }

    // half prologue: stage kt=0 into buf0 (safe per audit above)
#pragma unroll
    for (int i = 0; i < 2; ++i) {
      const int r = i * 32 + wv * 8 + stg_row;
      async_ld16(vp + (size_t)r * 2048 + stg_cg * 8, &Vt[0][(i * 32 + wv * 8) * 64]);
      async_ld16(kp + (size_t)r * 1024 + stg_cg * 8, &Ks[0][(i * 32 + wv * 8) * 64]);
    }

    for (int kt = 0; kt <= kb_max; ++kt) {
      const int k0 = kt * 64;
      const int cb = kt & 1;
      // own staging of buf[cb] (issued a full iter ago) + qf loads landed:
      asm volatile("s_waitcnt vmcnt(0)" ::: "memory");
      __builtin_amdgcn_s_barrier();  // all waves' buf[cb] staging visible

      if (kt < kb_max) {  // prefetch kt+1 into buf[cb^1]
        const int k1 = k0 + 64;
#pragma unroll
        for (int i = 0; i < 2; ++i) {
          const int r = i * 32 + wv * 8 + stg_row;
          async_ld16(vp + (size_t)r * 2048 + k1 + stg_cg * 8,
                     &Vt[cb ^ 1][(i * 32 + wv * 8) * 64]);
          async_ld16(kp + (size_t)(k1 + r) * 1024 + stg_cg * 8,
                     &Ks[cb ^ 1][(i * 32 + wv * 8) * 64]);
        }
      }

      if (kt <= kmax_w) {
        f32x4 s[2][4];
#pragma unroll
        for (int nq = 0; nq < 2; ++nq)
#pragma unroll
          for (int mi = 0; mi < 4; ++mi) s[nq][mi] = fz;
#pragma unroll
        for (int ds = 0; ds < 2; ++ds)
#pragma unroll
          for (int mi = 0; mi < 4; ++mi) {
            const bf16x8 ak =
                *(const bf16x8*)&Ks[cb][(mi * 16 + lr) * 64 + (((ds << 2) + quad) ^ swz) * 8];
            s[0][mi] = MFMA16(ak, qf[0][ds], s[0][mi]);
            s[1][mi] = MFMA16(ak, qf[1][ds], s[1][mi]);
          }

        if (kt < kmax_w) {
#pragma unroll
          for (int nq = 0; nq < 2; ++nq) {
            const int qloc = nq * 16 + lr;
#pragma unroll
            for (int mi = 0; mi < 4; ++mi) {
              bf16x4 pb;
#pragma unroll
              for (int r = 0; r < 4; ++r) pb[r] = (bf16)__builtin_amdgcn_exp2f(s[nq][mi][r]);
              *(bf16x4*)&Ps[wv][qloc * 72 + mi * 16 + quad * 4] = pb;
            }
          }
        } else {
          const int kofs = k0 - q0 - wv * 32;  // mask iff keyloc + kofs > qloc
#pragma unroll
          for (int nq = 0; nq < 2; ++nq) {
            const int qloc = nq * 16 + lr;
#pragma unroll
            for (int mi = 0; mi < 4; ++mi) {
              bf16x4 pb;
#pragma unroll
              for (int r = 0; r < 4; ++r) {
                float pv = __builtin_amdgcn_exp2f(s[nq][mi][r]);
                if (mi * 16 + quad * 4 + r + kofs > qloc) pv = 0.0f;
                pb[r] = (bf16)pv;
              }
              *(bf16x4*)&Ps[wv][qloc * 72 + mi * 16 + quad * 4] = pb;
            }
          }
        }

        bf16x8 ap[2][2];
#pragma unroll
        for (int ks = 0; ks < 2; ++ks) {
          ap[0][ks] = *(const bf16x8*)&Ps[wv][(lr) * 72 + ks * 32 + quad * 8];
          ap[1][ks] = *(const bf16x8*)&Ps[wv][(16 + lr) * 72 + ks * 32 + quad * 8];
        }
#pragma unroll
        for (int ks = 0; ks < 2; ++ks) {
          lacc[0] = MFMA16(ap[0][ks], ones, lacc[0]);
          lacc[1] = MFMA16(ap[1][ks], ones, lacc[1]);
#pragma unroll
          for (int nf = 0; nf < 4; ++nf) {
            const bf16x8 bv =
                *(const bf16x8*)&Vt[cb][(nf * 16 + lr) * 64 + (((ks << 2) + quad) ^ swz) * 8];
            o[0][nf] = MFMA16(ap[0][ks], bv, o[0][nf]);
            o[1][nf] = MFMA16(ap[1][ks], bv, o[1][nf]);
          }
        }
      }
    }

#pragma unroll
    for (int nq = 0; nq < 2; ++nq)
#pragma unroll
      for (int r = 0; r < 4; ++r) {
        const float inv = __builtin_amdgcn_rcpf(lacc[nq][r]);
        const int t = q0 + wv * 32 + nq * 16 + quad * 4 + r;
#pragma unroll
        for (int nf = 0; nf < 4; ++nf)
          yp[(size_t)t * 1024 + nf * 16 + lr] = (bf16)(o[nq][nf][r] * inv);
      }
  }
}

// ---------------------------------------------------------------------------
extern "C" void kernel_launch(void* const* d_in, const int* in_sizes, int n_in,
                              void* d_out, int out_size, void* d_ws, size_t ws_size,
                              hipStream_t stream) {
  const float* x      = (const float*)d_in[0];
  const float* w_qkv  = (const float*)d_in[1];
  const float* w_proj = (const float*)d_in[2];
  float* out = (float*)d_out;
  char* ws = (char*)d_ws;

  // workspace carve (88 MiB)
  bf16* xb   = (bf16*)(ws);                        // 16 MiB  [8192,1024]
  bf16* wqkb = (bf16*)(ws + (16ull << 20));        //  6 MiB  [3072,1024]
  bf16* wpb  = (bf16*)(ws + (22ull << 20));        //  2 MiB  [1024,1024]
  bf16* qb   = (bf16*)(ws + (24ull << 20));        // 16 MiB  [8192,1024] pre-scaled Q
  bf16* kbuf = (bf16*)(ws + (40ull << 20));        // 16 MiB  [8192,1024]
  bf16* vth  = (bf16*)(ws + (56ull << 20));        // 16 MiB  [64bh,64d,2048t]
  bf16* yb   = (bf16*)(ws + (72ull << 20));        // 16 MiB  [8192,1024]

  cast3_k<<<dim3(12288), 256, 0, stream>>>(x, w_qkv, w_proj, xb, wqkb, wpb);
  gemm_qkv<<<dim3(16, 64), 256, 0, stream>>>(xb, wqkb, qb, kbuf, vth);
  flash_attn10<<<dim3(8, 64), 256, 0, stream>>>(qb, kbuf, vth, yb);
  gemm_proj<<<dim3(8, 64), 256, 0, stream>>>(yb, wpb, out);
}